// Round 21
// baseline (55.778 us; speedup 1.0000x reference)
//
#include <hip/hip_runtime.h>
#include <hip/hip_bf16.h>

#define B_ 32
#define L_ 512
#define H_ 1024
#define E_ 8
#define R_ 16

typedef float f32x4 __attribute__((ext_vector_type(4)));
typedef __bf16 bf16x8 __attribute__((ext_vector_type(8)));
typedef __bf16 bf16x4 __attribute__((ext_vector_type(4)));

static __device__ __forceinline__ __bf16 f2b(float f) { return (__bf16)f; }

static __device__ __forceinline__ f32x4 MFMA(bf16x8 a, bf16x8 b, f32x4 c) {
  return __builtin_amdgcn_mfma_f32_16x16x32_bf16(a, b, c, 0, 0, 0);
}

// ---------------- prep: f32 weights -> bf16 in ws; + gates -----------------
__global__ __launch_bounds__(256) void moe_prep_kernel(
    const float* __restrict__ x, const float* __restrict__ rw,
    const float* __restrict__ ldown, const float* __restrict__ lup,
    __bf16* __restrict__ ldb, __bf16* __restrict__ lub,
    float* __restrict__ gws)
{
  const int bid = blockIdx.x;
  if (bid < 256) {
    const int base = bid * 1024 + threadIdx.x * 4;
    const float* src; __bf16* dst; int off;
    if (base < 131072) { src = ldown; dst = ldb; off = base; }
    else               { src = lup;   dst = lub; off = base - 131072; }
    float4 v = *(const float4*)(src + off);
    bf16x4 bv = { f2b(v.x), f2b(v.y), f2b(v.z), f2b(v.w) };
    *(bf16x4*)(dst + off) = bv;
    return;
  }
  const int b = bid - 256;
  const int t = threadIdx.x;
  const int e = t >> 5, s = t & 31;
  const float* cls = x + (size_t)b * L_ * H_;
  const float* w   = rw + (size_t)e * H_;
  float p = 0.f;
#pragma unroll
  for (int c = s; c < 256; c += 32) {
    float4 xv = *(const float4*)(cls + 4 * c);
    float4 wv = *(const float4*)(w + 4 * c);
    p += xv.x * wv.x + xv.y * wv.y + xv.z * wv.z + xv.w * wv.w;
  }
#pragma unroll
  for (int off = 16; off; off >>= 1) p += __shfl_down(p, off, 32);
  __shared__ float logits[E_];
  if (s == 0) logits[e] = p;
  __syncthreads();
  if (t == 0) {
    float m0 = -1e30f; int i0 = 0;
    for (int j = 0; j < E_; ++j) if (logits[j] > m0) { m0 = logits[j]; i0 = j; }
    float m1 = -1e30f; int i1 = 0;
    for (int j = 0; j < E_; ++j) if (j != i0 && logits[j] > m1) { m1 = logits[j]; i1 = j; }
    float eb = expf(m1 - m0), inv = 1.f / (1.f + eb);
    gws[b * 4 + 0] = inv;
    gws[b * 4 + 1] = eb * inv;
    ((int*)gws)[b * 4 + 2] = i0;
    ((int*)gws)[b * 4 + 3] = i1;
  }
}

// ---------------- gates-only fallback (no-ws path) -------------------------
__global__ __launch_bounds__(256) void moe_gates_kernel(
    const float* __restrict__ x, const float* __restrict__ rw,
    float* __restrict__ gws)
{
  const int b = blockIdx.x;
  const int t = threadIdx.x;
  const int e = t >> 5, s = t & 31;
  const float* cls = x + (size_t)b * L_ * H_;
  const float* w   = rw + (size_t)e * H_;
  float p = 0.f;
#pragma unroll
  for (int c = s; c < 256; c += 32) {
    float4 xv = *(const float4*)(cls + 4 * c);
    float4 wv = *(const float4*)(w + 4 * c);
    p += xv.x * wv.x + xv.y * wv.y + xv.z * wv.z + xv.w * wv.w;
  }
#pragma unroll
  for (int off = 16; off; off >>= 1) p += __shfl_down(p, off, 32);
  __shared__ float logits[E_];
  if (s == 0) logits[e] = p;
  __syncthreads();
  if (t == 0) {
    float m0 = -1e30f; int i0 = 0;
    for (int j = 0; j < E_; ++j) if (logits[j] > m0) { m0 = logits[j]; i0 = j; }
    float m1 = -1e30f; int i1 = 0;
    for (int j = 0; j < E_; ++j) if (j != i0 && logits[j] > m1) { m1 = logits[j]; i1 = j; }
    float eb = expf(m1 - m0), inv = 1.f / (1.f + eb);
    gws[b * 4 + 0] = inv;
    gws[b * 4 + 1] = eb * inv;
    ((int*)gws)[b * 4 + 2] = i0;
    ((int*)gws)[b * 4 + 3] = i1;
  }
}

// ---------------- main: ALL loads upfront (probe-shaped issue) -------------
// Per wave, one straight-line batch of 40 independent global loads (x slice,
// Wd frags, U frags) pinned above the phases by sched_barrier(0). In-order
// vmcnt: stage waits only for x, phase A only for +Wd, phase B for all.
// Raw s_barrier + lgkmcnt-only (NO __syncthreads: it would emit vmcnt(0)
// and drain the batch). Rest is R20-verbatim: wave-local stage, LDS-atomic
// K-reduce, direct dfrag, in-place bf16 phase B, streaming row epilogue.
template<int BW>
__global__ __launch_bounds__(512, 4) void moe_main_kernel(
    const float* __restrict__ x,
    const __bf16* __restrict__ ldb, const __bf16* __restrict__ lub,
    const float* __restrict__ ldf, const float* __restrict__ luf,
    const float* __restrict__ gws, float* __restrict__ out)
{
  constexpr int XW = 1036;                  // 518 dw/row, %32==6 (bank-spread)
  __shared__ __bf16 xs[16][XW];             // 33,152 B: x in, OUT (bf16) after B
  __shared__ float  dgf[2][16][16];         //  2,048 B: atomic K-reduce of D^T

  const int t    = threadIdx.x;
  const int w    = t >> 6;                  // 0..7
  const int lane = t & 63;
  const int gq   = lane >> 4;
  const int r16  = lane & 15;

  const int bid  = blockIdx.x;
  const int tile = (bid & 7) * 128 + (bid >> 3);   // XCD swizzle (bijective)
  const int b    = tile >> 5;
  const int l0   = (tile & 31) * 16;

  const float g0 = gws[b * 4 + 0];
  const float g1 = gws[b * 4 + 1];
  const int   e0 = ((const int*)gws)[b * 4 + 2];
  const int   e1 = ((const int*)gws)[b * 4 + 3];

  const int hr = lane >> 5;                 // 0,1
  const int cc = w * 128 + (lane & 31) * 4; // wave-local col slice

  // ================= ISSUE ALL GLOBAL LOADS (one batch) ====================
  const float* xb = x + ((size_t)b * L_ + l0 + hr) * H_ + cc;
  float4 xv0 = *(const float4*)(xb +  0 * H_);
  float4 xv1 = *(const float4*)(xb +  2 * H_);
  float4 xv2 = *(const float4*)(xb +  4 * H_);
  float4 xv3 = *(const float4*)(xb +  6 * H_);
  float4 xv4 = *(const float4*)(xb +  8 * H_);
  float4 xv5 = *(const float4*)(xb + 10 * H_);
  float4 xv6 = *(const float4*)(xb + 12 * H_);
  float4 xv7 = *(const float4*)(xb + 14 * H_);

  bf16x8 wf[4], uf[8];                      // assembled below from halves
  if constexpr (BW) {
    const __bf16* w0p = ldb + ((size_t)e0 * R_ + r16) * H_ + w * 128 + 4 * gq;
    const __bf16* w1p = ldb + ((size_t)e1 * R_ + r16) * H_ + w * 128 + 4 * gq;
    bf16x4 a0l = *(const bf16x4*)(w0p +  0), a0h = *(const bf16x4*)(w0p + 16);
    bf16x4 a1l = *(const bf16x4*)(w0p + 32), a1h = *(const bf16x4*)(w0p + 48);
    bf16x4 a2l = *(const bf16x4*)(w0p + 64), a2h = *(const bf16x4*)(w0p + 80);
    bf16x4 a3l = *(const bf16x4*)(w0p + 96), a3h = *(const bf16x4*)(w0p + 112);
    bf16x4 b0l = *(const bf16x4*)(w1p +  0), b0h = *(const bf16x4*)(w1p + 16);
    bf16x4 b1l = *(const bf16x4*)(w1p + 32), b1h = *(const bf16x4*)(w1p + 48);
    bf16x4 b2l = *(const bf16x4*)(w1p + 64), b2h = *(const bf16x4*)(w1p + 80);
    bf16x4 b3l = *(const bf16x4*)(w1p + 96), b3h = *(const bf16x4*)(w1p + 112);
    const __bf16* u0p = lub + ((size_t)e0 * H_ + w * 128 + r16) * R_ + 4 * gq;
    const __bf16* u1p = lub + ((size_t)e1 * H_ + w * 128 + r16) * R_ + 4 * gq;
    bf16x4 u0a = *(const bf16x4*)(u0p + 0 * 16 * R_);
    bf16x4 u1a = *(const bf16x4*)(u1p + 0 * 16 * R_);
    bf16x4 u0b = *(const bf16x4*)(u0p + 1 * 16 * R_);
    bf16x4 u1b = *(const bf16x4*)(u1p + 1 * 16 * R_);
    bf16x4 u0c = *(const bf16x4*)(u0p + 2 * 16 * R_);
    bf16x4 u1c = *(const bf16x4*)(u1p + 2 * 16 * R_);
    bf16x4 u0d = *(const bf16x4*)(u0p + 3 * 16 * R_);
    bf16x4 u1d = *(const bf16x4*)(u1p + 3 * 16 * R_);
    bf16x4 u0e = *(const bf16x4*)(u0p + 4 * 16 * R_);
    bf16x4 u1e = *(const bf16x4*)(u1p + 4 * 16 * R_);
    bf16x4 u0f = *(const bf16x4*)(u0p + 5 * 16 * R_);
    bf16x4 u1f = *(const bf16x4*)(u1p + 5 * 16 * R_);
    bf16x4 u0g = *(const bf16x4*)(u0p + 6 * 16 * R_);
    bf16x4 u1g = *(const bf16x4*)(u1p + 6 * 16 * R_);
    bf16x4 u0h = *(const bf16x4*)(u0p + 7 * 16 * R_);
    bf16x4 u1h = *(const bf16x4*)(u1p + 7 * 16 * R_);
    __builtin_amdgcn_sched_barrier(0);      // pin: no sinking past this point
    wf[0] = bf16x8{ a0l[0],a0l[1],a0l[2],a0l[3], a0h[0],a0h[1],a0h[2],a0h[3] };
    wf[1] = bf16x8{ a1l[0],a1l[1],a1l[2],a1l[3], a1h[0],a1h[1],a1h[2],a1h[3] };
    wf[2] = bf16x8{ a2l[0],a2l[1],a2l[2],a2l[3], a2h[0],a2h[1],a2h[2],a2h[3] };
    wf[3] = bf16x8{ a3l[0],a3l[1],a3l[2],a3l[3], a3h[0],a3h[1],a3h[2],a3h[3] };
    // second expert packed into the high half via a second array:
    // store as wf2[] below to keep compile-time indexing
    bf16x8 wg0 = bf16x8{ b0l[0],b0l[1],b0l[2],b0l[3], b0h[0],b0h[1],b0h[2],b0h[3] };
    bf16x8 wg1 = bf16x8{ b1l[0],b1l[1],b1l[2],b1l[3], b1h[0],b1h[1],b1h[2],b1h[3] };
    bf16x8 wg2 = bf16x8{ b2l[0],b2l[1],b2l[2],b2l[3], b2h[0],b2h[1],b2h[2],b2h[3] };
    bf16x8 wg3 = bf16x8{ b3l[0],b3l[1],b3l[2],b3l[3], b3h[0],b3h[1],b3h[2],b3h[3] };
    uf[0] = bf16x8{ u0a[0],u0a[1],u0a[2],u0a[3], u1a[0],u1a[1],u1a[2],u1a[3] };
    uf[1] = bf16x8{ u0b[0],u0b[1],u0b[2],u0b[3], u1b[0],u1b[1],u1b[2],u1b[3] };
    uf[2] = bf16x8{ u0c[0],u0c[1],u0c[2],u0c[3], u1c[0],u1c[1],u1c[2],u1c[3] };
    uf[3] = bf16x8{ u0d[0],u0d[1],u0d[2],u0d[3], u1d[0],u1d[1],u1d[2],u1d[3] };
    uf[4] = bf16x8{ u0e[0],u0e[1],u0e[2],u0e[3], u1e[0],u1e[1],u1e[2],u1e[3] };
    uf[5] = bf16x8{ u0f[0],u0f[1],u0f[2],u0f[3], u1f[0],u1f[1],u1f[2],u1f[3] };
    uf[6] = bf16x8{ u0g[0],u0g[1],u0g[2],u0g[3], u1g[0],u1g[1],u1g[2],u1g[3] };
    uf[7] = bf16x8{ u0h[0],u0h[1],u0h[2],u0h[3], u1h[0],u1h[1],u1h[2],u1h[3] };

    // ---- dgf zero + barrier (lgkm-only; keeps the batch in flight) --------
    ((float*)dgf)[t] = 0.f;
    asm volatile("s_waitcnt lgkmcnt(0)" ::: "memory");
    __builtin_amdgcn_s_barrier();

    // ---- stage: consume x batch into wave-local col slice -----------------
    {
      bf16x4 s0 = { f2b(xv0.x), f2b(xv0.y), f2b(xv0.z), f2b(xv0.w) };
      bf16x4 s1 = { f2b(xv1.x), f2b(xv1.y), f2b(xv1.z), f2b(xv1.w) };
      bf16x4 s2 = { f2b(xv2.x), f2b(xv2.y), f2b(xv2.z), f2b(xv2.w) };
      bf16x4 s3 = { f2b(xv3.x), f2b(xv3.y), f2b(xv3.z), f2b(xv3.w) };
      bf16x4 s4 = { f2b(xv4.x), f2b(xv4.y), f2b(xv4.z), f2b(xv4.w) };
      bf16x4 s5 = { f2b(xv5.x), f2b(xv5.y), f2b(xv5.z), f2b(xv5.w) };
      bf16x4 s6 = { f2b(xv6.x), f2b(xv6.y), f2b(xv6.z), f2b(xv6.w) };
      bf16x4 s7 = { f2b(xv7.x), f2b(xv7.y), f2b(xv7.z), f2b(xv7.w) };
      *(bf16x4*)&xs[ 0 + hr][cc] = s0;
      *(bf16x4*)&xs[ 2 + hr][cc] = s1;
      *(bf16x4*)&xs[ 4 + hr][cc] = s2;
      *(bf16x4*)&xs[ 6 + hr][cc] = s3;
      *(bf16x4*)&xs[ 8 + hr][cc] = s4;
      *(bf16x4*)&xs[10 + hr][cc] = s5;
      *(bf16x4*)&xs[12 + hr][cc] = s6;
      *(bf16x4*)&xs[14 + hr][cc] = s7;
    }

    // ---- phase A: wave-local K slice; weights already in regs -------------
    f32x4 acc0 = {0.f, 0.f, 0.f, 0.f};
    f32x4 acc1 = {0.f, 0.f, 0.f, 0.f};
#pragma unroll
    for (int s = 0; s < 4; ++s) {
      const int kl = w * 128 + s * 32 + 4 * gq;
      bf16x4 xlo = *(const bf16x4*)&xs[r16][kl];
      bf16x4 xhi = *(const bf16x4*)&xs[r16][kl + 16];
      bf16x8 xq = { xlo[0], xlo[1], xlo[2], xlo[3],
                    xhi[0], xhi[1], xhi[2], xhi[3] };
      bf16x8 w1q = (s == 0) ? wg0 : (s == 1) ? wg1 : (s == 2) ? wg2 : wg3;
      acc0 = MFMA(wf[s], xq, acc0);
      acc1 = MFMA(w1q, xq, acc1);
    }
#pragma unroll
    for (int j = 0; j < 4; ++j) {
      atomicAdd(&dgf[0][r16][4 * gq + j], acc0[j]);
      atomicAdd(&dgf[1][r16][4 * gq + j], acc1[j]);
    }
    asm volatile("s_waitcnt lgkmcnt(0)" ::: "memory");
    __builtin_amdgcn_s_barrier();

    // ---- phase B: dfrag direct from dgf; U already in regs ----------------
    bf16x8 dfrag;
#pragma unroll
    for (int j = 0; j < 4; ++j) {
      dfrag[j]     = f2b(dgf[0][r16][4 * gq + j] * g0);
      dfrag[4 + j] = f2b(dgf[1][r16][4 * gq + j] * g1);
    }
#pragma unroll
    for (int nt = 0; nt < 8; ++nt) {
      const int h0 = w * 128 + nt * 16;
      bf16x4 rx = *(const bf16x4*)&xs[r16][h0 + 4 * gq];
      f32x4 acc = { (float)rx[0], (float)rx[1], (float)rx[2], (float)rx[3] };
      acc = MFMA(uf[nt], dfrag, acc);
      bf16x4 ov = { f2b(acc[0]), f2b(acc[1]), f2b(acc[2]), f2b(acc[3]) };
      *(bf16x4*)&xs[r16][h0 + 4 * gq] = ov;
    }
    asm volatile("s_waitcnt lgkmcnt(0)" ::: "memory");
    __builtin_amdgcn_s_barrier();
  } else {
    // -------- f32-weight fallback: R20-style in-phase loads ----------------
    ((float*)dgf)[t] = 0.f;
    __syncthreads();
    {
      bf16x4 s0 = { f2b(xv0.x), f2b(xv0.y), f2b(xv0.z), f2b(xv0.w) };
      bf16x4 s1 = { f2b(xv1.x), f2b(xv1.y), f2b(xv1.z), f2b(xv1.w) };
      bf16x4 s2 = { f2b(xv2.x), f2b(xv2.y), f2b(xv2.z), f2b(xv2.w) };
      bf16x4 s3 = { f2b(xv3.x), f2b(xv3.y), f2b(xv3.z), f2b(xv3.w) };
      bf16x4 s4 = { f2b(xv4.x), f2b(xv4.y), f2b(xv4.z), f2b(xv4.w) };
      bf16x4 s5 = { f2b(xv5.x), f2b(xv5.y), f2b(xv5.z), f2b(xv5.w) };
      bf16x4 s6 = { f2b(xv6.x), f2b(xv6.y), f2b(xv6.z), f2b(xv6.w) };
      bf16x4 s7 = { f2b(xv7.x), f2b(xv7.y), f2b(xv7.z), f2b(xv7.w) };
      *(bf16x4*)&xs[ 0 + hr][cc] = s0;  *(bf16x4*)&xs[ 2 + hr][cc] = s1;
      *(bf16x4*)&xs[ 4 + hr][cc] = s2;  *(bf16x4*)&xs[ 6 + hr][cc] = s3;
      *(bf16x4*)&xs[ 8 + hr][cc] = s4;  *(bf16x4*)&xs[10 + hr][cc] = s5;
      *(bf16x4*)&xs[12 + hr][cc] = s6;  *(bf16x4*)&xs[14 + hr][cc] = s7;
    }
    f32x4 acc0 = {0.f, 0.f, 0.f, 0.f};
    f32x4 acc1 = {0.f, 0.f, 0.f, 0.f};
#pragma unroll
    for (int s = 0; s < 4; ++s) {
      const int kl = w * 128 + s * 32 + 4 * gq;
      bf16x4 xlo = *(const bf16x4*)&xs[r16][kl];
      bf16x4 xhi = *(const bf16x4*)&xs[r16][kl + 16];
      bf16x8 xq = { xlo[0], xlo[1], xlo[2], xlo[3],
                    xhi[0], xhi[1], xhi[2], xhi[3] };
      const float* w0p = ldf + ((size_t)e0 * R_ + r16) * H_;
      const float* w1p = ldf + ((size_t)e1 * R_ + r16) * H_;
      float4 alo = *(const float4*)(w0p + kl);
      float4 ahi = *(const float4*)(w0p + kl + 16);
      float4 blo = *(const float4*)(w1p + kl);
      float4 bhi = *(const float4*)(w1p + kl + 16);
      bf16x8 wf0 = { f2b(alo.x), f2b(alo.y), f2b(alo.z), f2b(alo.w),
                     f2b(ahi.x), f2b(ahi.y), f2b(ahi.z), f2b(ahi.w) };
      bf16x8 wf1 = { f2b(blo.x), f2b(blo.y), f2b(blo.z), f2b(blo.w),
                     f2b(bhi.x), f2b(bhi.y), f2b(bhi.z), f2b(bhi.w) };
      acc0 = MFMA(wf0, xq, acc0);
      acc1 = MFMA(wf1, xq, acc1);
    }
#pragma unroll
    for (int j = 0; j < 4; ++j) {
      atomicAdd(&dgf[0][r16][4 * gq + j], acc0[j]);
      atomicAdd(&dgf[1][r16][4 * gq + j], acc1[j]);
    }
    __syncthreads();
    bf16x8 dfrag;
#pragma unroll
    for (int j = 0; j < 4; ++j) {
      dfrag[j]     = f2b(dgf[0][r16][4 * gq + j] * g0);
      dfrag[4 + j] = f2b(dgf[1][r16][4 * gq + j] * g1);
    }
#pragma unroll
    for (int nt = 0; nt < 8; ++nt) {
      const int h0 = w * 128 + nt * 16;
      const int ha = h0 + r16;
      float4 ulo = *(const float4*)(luf + ((size_t)e0 * H_ + ha) * R_ + 4 * gq);
      float4 uhi = *(const float4*)(luf + ((size_t)e1 * H_ + ha) * R_ + 4 * gq);
      bf16x8 ufq = { f2b(ulo.x), f2b(ulo.y), f2b(ulo.z), f2b(ulo.w),
                     f2b(uhi.x), f2b(uhi.y), f2b(uhi.z), f2b(uhi.w) };
      bf16x4 rx = *(const bf16x4*)&xs[r16][h0 + 4 * gq];
      f32x4 acc = { (float)rx[0], (float)rx[1], (float)rx[2], (float)rx[3] };
      acc = MFMA(ufq, dfrag, acc);
      bf16x4 ov = { f2b(acc[0]), f2b(acc[1]), f2b(acc[2]), f2b(acc[3]) };
      *(bf16x4*)&xs[r16][h0 + 4 * gq] = ov;
    }
    __syncthreads();
  }

  // ---- epilogue: stream whole rows out (512B contiguous per instruction) --
  {
    const int row = 2 * w + hr;
    const int l32 = lane & 31;
    float* outrow = out + ((size_t)b * L_ + l0 + row) * H_;
#pragma unroll
    for (int it = 0; it < 8; ++it) {
      const int col = it * 128 + l32 * 4;
      bf16x4 v = *(const bf16x4*)&xs[row][col];
      float4 o = { (float)v[0], (float)v[1], (float)v[2], (float)v[3] };
      *(float4*)(outrow + col) = o;
    }
  }
}

extern "C" void kernel_launch(void* const* d_in, const int* in_sizes, int n_in,
                              void* d_out, int out_size, void* d_ws, size_t ws_size,
                              hipStream_t stream) {
  const float* x  = (const float*)d_in[0];
  const float* rw = (const float*)d_in[1];
  const float* ld = (const float*)d_in[2];
  const float* lu = (const float*)d_in[3];
  float* outp = (float*)d_out;

  float*  gws = (float*)d_ws;                         // 512 B
  __bf16* ldb = (__bf16*)((char*)d_ws + 1024);        // 256 KB
  __bf16* lub = ldb + 131072;                         // 256 KB

  if (ws_size >= 1024 + 2 * 131072 * sizeof(__bf16)) {
    hipLaunchKernelGGL(moe_prep_kernel, dim3(256 + B_), dim3(256), 0, stream,
                       x, rw, ld, lu, ldb, lub, gws);
    hipLaunchKernelGGL(moe_main_kernel<1>, dim3(1024), dim3(512), 0, stream,
                       x, ldb, lub, nullptr, nullptr, gws, outp);
  } else {
    hipLaunchKernelGGL(moe_gates_kernel, dim3(B_), dim3(256), 0, stream,
                       x, rw, gws);
    hipLaunchKernelGGL(moe_main_kernel<0>, dim3(1024), dim3(512), 0, stream,
                       x, nullptr, nullptr, ld, lu, gws, outp);
  }
}

// Round 22
// 43.013 us; speedup vs baseline: 1.2968x; 1.2968x over previous
//
#include <hip/hip_runtime.h>
#include <hip/hip_bf16.h>

#define B_ 32
#define L_ 512
#define H_ 1024
#define E_ 8
#define R_ 16

typedef float f32x4 __attribute__((ext_vector_type(4)));
typedef __bf16 bf16x8 __attribute__((ext_vector_type(8)));
typedef __bf16 bf16x4 __attribute__((ext_vector_type(4)));

static __device__ __forceinline__ __bf16 f2b(float f) { return (__bf16)f; }

static __device__ __forceinline__ f32x4 MFMA(bf16x8 a, bf16x8 b, f32x4 c) {
  return __builtin_amdgcn_mfma_f32_16x16x32_bf16(a, b, c, 0, 0, 0);
}

// ---------------- prep: f32 weights -> bf16 in ws; + gates -----------------
__global__ __launch_bounds__(256) void moe_prep_kernel(
    const float* __restrict__ x, const float* __restrict__ rw,
    const float* __restrict__ ldown, const float* __restrict__ lup,
    __bf16* __restrict__ ldb, __bf16* __restrict__ lub,
    float* __restrict__ gws)
{
  const int bid = blockIdx.x;
  if (bid < 256) {                          // weight conversion: 2x131072 f32
    const int base = bid * 1024 + threadIdx.x * 4;
    const float* src; __bf16* dst; int off;
    if (base < 131072) { src = ldown; dst = ldb; off = base; }
    else               { src = lup;   dst = lub; off = base - 131072; }
    float4 v = *(const float4*)(src + off);
    bf16x4 bv = { f2b(v.x), f2b(v.y), f2b(v.z), f2b(v.w) };
    *(bf16x4*)(dst + off) = bv;
    return;
  }
  // gates for b = bid - 256
  const int b = bid - 256;
  const int t = threadIdx.x;
  const int e = t >> 5, s = t & 31;
  const float* cls = x + (size_t)b * L_ * H_;
  const float* w   = rw + (size_t)e * H_;
  float p = 0.f;
#pragma unroll
  for (int c = s; c < 256; c += 32) {
    float4 xv = *(const float4*)(cls + 4 * c);
    float4 wv = *(const float4*)(w + 4 * c);
    p += xv.x * wv.x + xv.y * wv.y + xv.z * wv.z + xv.w * wv.w;
  }
#pragma unroll
  for (int off = 16; off; off >>= 1) p += __shfl_down(p, off, 32);
  __shared__ float logits[E_];
  if (s == 0) logits[e] = p;
  __syncthreads();
  if (t == 0) {
    float m0 = -1e30f; int i0 = 0;
    for (int j = 0; j < E_; ++j) if (logits[j] > m0) { m0 = logits[j]; i0 = j; }
    float m1 = -1e30f; int i1 = 0;
    for (int j = 0; j < E_; ++j) if (j != i0 && logits[j] > m1) { m1 = logits[j]; i1 = j; }
    float eb = expf(m1 - m0), inv = 1.f / (1.f + eb);
    gws[b * 4 + 0] = inv;
    gws[b * 4 + 1] = eb * inv;
    ((int*)gws)[b * 4 + 2] = i0;
    ((int*)gws)[b * 4 + 3] = i1;
  }
}

// ---------------- gates-only fallback (no-ws path) -------------------------
__global__ __launch_bounds__(256) void moe_gates_kernel(
    const float* __restrict__ x, const float* __restrict__ rw,
    float* __restrict__ gws)
{
  const int b = blockIdx.x;
  const int t = threadIdx.x;
  const int e = t >> 5, s = t & 31;
  const float* cls = x + (size_t)b * L_ * H_;
  const float* w   = rw + (size_t)e * H_;
  float p = 0.f;
#pragma unroll
  for (int c = s; c < 256; c += 32) {
    float4 xv = *(const float4*)(cls + 4 * c);
    float4 wv = *(const float4*)(w + 4 * c);
    p += xv.x * wv.x + xv.y * wv.y + xv.z * wv.z + xv.w * wv.w;
  }
#pragma unroll
  for (int off = 16; off; off >>= 1) p += __shfl_down(p, off, 32);
  __shared__ float logits[E_];
  if (s == 0) logits[e] = p;
  __syncthreads();
  if (t == 0) {
    float m0 = -1e30f; int i0 = 0;
    for (int j = 0; j < E_; ++j) if (logits[j] > m0) { m0 = logits[j]; i0 = j; }
    float m1 = -1e30f; int i1 = 0;
    for (int j = 0; j < E_; ++j) if (j != i0 && logits[j] > m1) { m1 = logits[j]; i1 = j; }
    float eb = expf(m1 - m0), inv = 1.f / (1.f + eb);
    gws[b * 4 + 0] = inv;
    gws[b * 4 + 1] = eb * inv;
    ((int*)gws)[b * 4 + 2] = i0;
    ((int*)gws)[b * 4 + 3] = i1;
  }
}

// ---------------- main: R14 verbatim (best measured: 43.1 us total) --------
// Stage bf16 X tile -> phase A (swapped-operand MFMA, K-split across 8
// waves) -> LDS reduce + gate -> phase B (transposed MFMA, in-place bf16
// results over the residual quads) -> streaming row epilogue (512B
// contiguous stores). Row stride 1036 elems (518 dw, %32==6) spreads rows
// across banks.
template<int BW>
__global__ __launch_bounds__(512, 4) void moe_main_kernel(
    const float* __restrict__ x,
    const __bf16* __restrict__ ldb, const __bf16* __restrict__ lub,
    const float* __restrict__ ldf, const float* __restrict__ luf,
    const float* __restrict__ gws, float* __restrict__ out)
{
  constexpr int XW = 1036;
  __shared__ __bf16 xs[16][XW];             // 33,152 B: x in, OUT (bf16) after B
  __shared__ f32x4  red[8][2][64];          // 16,384 B
  __shared__ __bf16 dg[16][40];             //  1,280 B

  const int t    = threadIdx.x;
  const int w    = t >> 6;                  // 0..7
  const int lane = t & 63;
  const int gq   = lane >> 4;
  const int r16  = lane & 15;

  const int bid  = blockIdx.x;
  const int tile = (bid & 7) * 128 + (bid >> 3);   // XCD swizzle (bijective)
  const int b    = tile >> 5;
  const int l0   = (tile & 31) * 16;

  const float g0 = gws[b * 4 + 0];
  const float g1 = gws[b * 4 + 1];
  const int   e0 = ((const int*)gws)[b * 4 + 2];
  const int   e1 = ((const int*)gws)[b * 4 + 3];

  const float* xb = x + ((size_t)b * L_ + l0) * H_;

  // ---- stage X tile as bf16 (wave w: rows 2w,2w+1; row-contiguous reads) --
  {
    const int row = 2 * w + (lane >> 5);
    const int c0  = (lane & 31) * 4;
    const float* xrr = xb + (size_t)row * H_;
#pragma unroll
    for (int i = 0; i < 8; ++i) {
      float4 v = *(const float4*)(xrr + c0 + i * 128);
      bf16x4 bv = { f2b(v.x), f2b(v.y), f2b(v.z), f2b(v.w) };
      *(bf16x4*)&xs[row][c0 + i * 128] = bv;
    }
  }
  __syncthreads();

  // ---- Phase A: wave w handles K slice [w*128, (w+1)*128) -----------------
  f32x4 acc0 = {0.f, 0.f, 0.f, 0.f};
  f32x4 acc1 = {0.f, 0.f, 0.f, 0.f};
#pragma unroll
  for (int s = 0; s < 4; ++s) {
    const int kl = w * 128 + s * 32 + 4 * gq;
    bf16x4 xlo = *(const bf16x4*)&xs[r16][kl];
    bf16x4 xhi = *(const bf16x4*)&xs[r16][kl + 16];
    bf16x8 xq = { xlo[0], xlo[1], xlo[2], xlo[3],
                  xhi[0], xhi[1], xhi[2], xhi[3] };
    bf16x8 wf0, wf1;
    if constexpr (BW) {
      const __bf16* w0p = ldb + ((size_t)e0 * R_ + r16) * H_;
      const __bf16* w1p = ldb + ((size_t)e1 * R_ + r16) * H_;
      bf16x4 a0 = *(const bf16x4*)(w0p + kl);
      bf16x4 a1 = *(const bf16x4*)(w0p + kl + 16);
      bf16x4 b0 = *(const bf16x4*)(w1p + kl);
      bf16x4 b1 = *(const bf16x4*)(w1p + kl + 16);
      wf0 = bf16x8{ a0[0],a0[1],a0[2],a0[3], a1[0],a1[1],a1[2],a1[3] };
      wf1 = bf16x8{ b0[0],b0[1],b0[2],b0[3], b1[0],b1[1],b1[2],b1[3] };
    } else {
      const float* w0p = ldf + ((size_t)e0 * R_ + r16) * H_;
      const float* w1p = ldf + ((size_t)e1 * R_ + r16) * H_;
      float4 alo = *(const float4*)(w0p + kl);
      float4 ahi = *(const float4*)(w0p + kl + 16);
      float4 blo = *(const float4*)(w1p + kl);
      float4 bhi = *(const float4*)(w1p + kl + 16);
      wf0 = bf16x8{ f2b(alo.x), f2b(alo.y), f2b(alo.z), f2b(alo.w),
                    f2b(ahi.x), f2b(ahi.y), f2b(ahi.z), f2b(ahi.w) };
      wf1 = bf16x8{ f2b(blo.x), f2b(blo.y), f2b(blo.z), f2b(blo.w),
                    f2b(bhi.x), f2b(bhi.y), f2b(bhi.z), f2b(bhi.w) };
    }
    acc0 = MFMA(wf0, xq, acc0);
    acc1 = MFMA(wf1, xq, acc1);
  }
  red[w][0][lane] = acc0;
  red[w][1][lane] = acc1;
  __syncthreads();

  // ---- reduce 8 K-parts + gate + pack dg[l][p] (D^T frag layout) ----------
  if (t < 128) {
    const int tl = t >> 6, slot = t & 63;
    f32x4 v = red[0][tl][slot];
#pragma unroll
    for (int q = 1; q < 8; ++q) v += red[q][tl][slot];
    const float g = tl ? g1 : g0;
    const int l  = slot & 15;
    const int p0 = tl * 16 + (slot >> 4) * 4;
#pragma unroll
    for (int j = 0; j < 4; ++j) dg[l][p0 + j] = f2b(v[j] * g);
  }
  __syncthreads();

  // ---- Phase B: wave w covers h in [w*128, (w+1)*128); in-place results ---
  bf16x8 dfrag;
#pragma unroll
  for (int j = 0; j < 4; ++j) {
    dfrag[j]     = dg[r16][4 * gq + j];         // k=4gq+j      (e0)
    dfrag[4 + j] = dg[r16][16 + 4 * gq + j];    // k=16+4gq+j   (e1)
  }

#pragma unroll
  for (int nt = 0; nt < 8; ++nt) {
    const int h0 = w * 128 + nt * 16;
    const int ha = h0 + r16;
    bf16x8 uf;
    if constexpr (BW) {
      bf16x4 ulo = *(const bf16x4*)(lub + ((size_t)e0 * H_ + ha) * R_ + 4 * gq);
      bf16x4 uhi = *(const bf16x4*)(lub + ((size_t)e1 * H_ + ha) * R_ + 4 * gq);
      uf = bf16x8{ ulo[0],ulo[1],ulo[2],ulo[3], uhi[0],uhi[1],uhi[2],uhi[3] };
    } else {
      float4 ulo = *(const float4*)(luf + ((size_t)e0 * H_ + ha) * R_ + 4 * gq);
      float4 uhi = *(const float4*)(luf + ((size_t)e1 * H_ + ha) * R_ + 4 * gq);
      uf = bf16x8{ f2b(ulo.x), f2b(ulo.y), f2b(ulo.z), f2b(ulo.w),
                   f2b(uhi.x), f2b(uhi.y), f2b(uhi.z), f2b(uhi.w) };
    }
    bf16x4 rx = *(const bf16x4*)&xs[r16][h0 + 4 * gq];    // residual (bf16)
    f32x4 acc = { (float)rx[0], (float)rx[1], (float)rx[2], (float)rx[3] };
    acc = MFMA(uf, dfrag, acc);
    bf16x4 ov = { f2b(acc[0]), f2b(acc[1]), f2b(acc[2]), f2b(acc[3]) };
    *(bf16x4*)&xs[r16][h0 + 4 * gq] = ov;     // in-place: same lane, same quad
  }
  __syncthreads();

  // ---- epilogue: stream whole rows out (512B contiguous per instruction) --
  {
    const int row = 2 * w + (lane >> 5);
    const int l32 = lane & 31;
    float* outrow = out + ((size_t)b * L_ + l0 + row) * H_;
#pragma unroll
    for (int it = 0; it < 8; ++it) {
      const int col = it * 128 + l32 * 4;
      bf16x4 v = *(const bf16x4*)&xs[row][col];
      float4 o = { (float)v[0], (float)v[1], (float)v[2], (float)v[3] };
      *(float4*)(outrow + col) = o;
    }
  }
}

extern "C" void kernel_launch(void* const* d_in, const int* in_sizes, int n_in,
                              void* d_out, int out_size, void* d_ws, size_t ws_size,
                              hipStream_t stream) {
  const float* x  = (const float*)d_in[0];
  const float* rw = (const float*)d_in[1];
  const float* ld = (const float*)d_in[2];
  const float* lu = (const float*)d_in[3];
  float* outp = (float*)d_out;

  float*  gws = (float*)d_ws;                         // 512 B
  __bf16* ldb = (__bf16*)((char*)d_ws + 1024);        // 256 KB
  __bf16* lub = ldb + 131072;                         // 256 KB

  if (ws_size >= 1024 + 2 * 131072 * sizeof(__bf16)) {
    hipLaunchKernelGGL(moe_prep_kernel, dim3(256 + B_), dim3(256), 0, stream,
                       x, rw, ld, lu, ldb, lub, gws);
    hipLaunchKernelGGL(moe_main_kernel<1>, dim3(1024), dim3(512), 0, stream,
                       x, ldb, lub, nullptr, nullptr, gws, outp);
  } else {
    hipLaunchKernelGGL(moe_gates_kernel, dim3(B_), dim3(256), 0, stream,
                       x, rw, gws);
    hipLaunchKernelGGL(moe_main_kernel<0>, dim3(1024), dim3(512), 0, stream,
                       x, nullptr, nullptr, ld, lu, gws, outp);
  }
}